// Round 7
// baseline (25.186 us; speedup 1.0000x reference)
//
#include <hip/hip_runtime.h>

#define BB 8
#define HH 256
#define WW 256
#define BHW (BB*HH*WW)
#define BIGV 512.0f

// Fully fused: grid = 64 blocks = ip(2) x b(8) x row-quarter(4), 1024 threads.
// Each block computes vertical EDT summaries for the WHOLE image (phase A),
// exact per-pixel vertical distances for its own 64-row window (LDS u16,
// bit15 = mask), then the horizontal min-search + loss for those rows.
// Loss decomposes: sum_pix err*(dtx^2+dty^2) = [x-blocks] err*dtx^2 + [y] err*dty^2.
__global__ __launch_bounds__(1024) void hausdorff_fused(
        const float* __restrict__ x, const float* __restrict__ y,
        float* __restrict__ partials) {
    __shared__ float Cf[2][4][256];       // [ch][quarter][col] fwd summaries
    __shared__ float Cb[2][4][256];       // [ch][quarter][col] bwd summaries
    __shared__ unsigned short gq[64][256];// window rows: bit15=mask, low bits=dist
    __shared__ int sAny;
    __shared__ float wsum[16];

    int blk = blockIdx.x;
    int qt = blk & 3;                     // this block's row quarter
    int b  = (blk >> 2) & 7;
    int ip = blk >> 5;                    // 0 = x, 1 = y
    int t = threadIdx.x;
    int c = t & 255;                      // column
    int q = t >> 8;                       // quarter this thread scans

    if (t == 0) sAny = 0;

    const float* img = (ip ? y : x) + (size_t)b * (HH*WW);

    // ---- Phase A: column scan, 64 rows per thread (coalesced across lanes) ----
    unsigned long long m = 0ull;
    {
        const float* p = img + (size_t)(q*64)*WW + c;
        for (int i = 0; i < 64; ++i)
            if (p[(size_t)i*WW] > 0.5f) m |= (1ull << i);
    }
    unsigned long long zf = ~m;           // zeros of fg channel
    unsigned long long zb = m;            // zeros of bg channel
    Cf[0][q][c] = zf ? (float)__clzll((long long)zf) : 1e9f;   // dist from quarter end to last zero
    Cb[0][q][c] = zf ? (float)(__ffsll(zf) - 1)      : 1e9f;   // dist from quarter start to first zero
    Cf[1][q][c] = zb ? (float)__clzll((long long)zb) : 1e9f;
    Cb[1][q][c] = zb ? (float)(__ffsll(zb) - 1)      : 1e9f;
    __syncthreads();
    if (m) sAny = 1;                      // whole-image any-fg (benign race, after init barrier)

    if (q == qt) {                        // wave-uniform: only target-quarter waves
        // carries entering quarter qt (3 predicated steps each direction)
        float e0 = BIGV, e1 = BIGV;
        #pragma unroll
        for (int qp = 0; qp < 3; ++qp) {
            bool act = qp < qt;
            float c0 = Cf[0][qp][c], c1 = Cf[1][qp][c];
            e0 = act ? fminf(fminf(e0 + 64.0f, BIGV), c0) : e0;
            e1 = act ? fminf(fminf(e1 + 64.0f, BIGV), c1) : e1;
        }
        float f0 = BIGV, f1 = BIGV;
        #pragma unroll
        for (int qp = 3; qp >= 1; --qp) {
            bool act = qp > qt;
            float c0 = Cb[0][qp][c], c1 = Cb[1][qp][c];
            f0 = act ? fminf(fminf(f0 + 64.0f, BIGV), c0) : f0;
            f1 = act ? fminf(fminf(f1 + 64.0f, BIGV), c1) : f1;
        }
        // backward detail -> LDS
        float d0 = f0, d1 = f1;
        for (int i = 63; i >= 0; --i) {
            bool bit = (m >> i) & 1ull;
            d0 = !bit ? 0.0f : fminf(d0 + 1.0f, BIGV);
            d1 =  bit ? 0.0f : fminf(d1 + 1.0f, BIGV);
            float gs = bit ? d0 : d1;     // exactly one channel nonzero per pixel
            gq[i][c] = (unsigned short)(((int)bit << 15) | (int)gs);
        }
        // forward detail + min + store
        d0 = e0; d1 = e1;
        for (int i = 0; i < 64; ++i) {
            bool bit = (m >> i) & 1ull;
            d0 = !bit ? 0.0f : fminf(d0 + 1.0f, BIGV);
            d1 =  bit ? 0.0f : fminf(d1 + 1.0f, BIGV);
            float fs = bit ? d0 : d1;
            int prev = gq[i][c] & 0x3FF;
            float gs = fminf(fs, (float)prev);
            gq[i][c] = (unsigned short)(((int)bit << 15) | (int)gs);
        }
    }
    __syncthreads();

    // ---- Phase B: horizontal search + fused loss, 2 rows interleaved/thread ----
    int j = c;
    int rs = q;                           // lane-row group 0..3; wave handles one row at a time
    bool hf = sAny != 0;
    const float* xb = x + (size_t)b*(HH*WW);
    const float* yb = y + (size_t)b*(HH*WW);
    float acc = 0.0f;
    for (int k = 0; k < 8; ++k) {
        int r1 = rs + k*8;                // local rows; pair for 2x ILP
        int r2 = r1 + 4;
        unsigned v1 = gq[r1][j], v2 = gq[r2][j];
        int gA = v1 & 0x3FF, gB = v2 & 0x3FF;
        float a2 = (float)(gA*gA), bsq = (float)(gB*gB);
        bool bitA = (v1 >> 15) != 0, bitB = (v2 >> 15) != 0;
        float a0 = bitA ? a2 : 0.0f, a1 = bitA ? 0.0f : a2;
        float c0 = bitB ? bsq : 0.0f, c1 = bitB ? 0.0f : bsq;
        int gr1 = qt*64 + r1, gr2 = qt*64 + r2;
        float xv1 = xb[(size_t)gr1*WW + j], yv1 = yb[(size_t)gr1*WW + j];
        float xv2 = xb[(size_t)gr2*WW + j], yv2 = yb[(size_t)gr2*WW + j];
        for (int dl = 1; dl < 256; ++dl) {
            float d2 = (float)(dl*dl);
            float mx = fmaxf(fmaxf(a0, a1), fmaxf(c0, c1));
            if (!__any(d2 < mx)) break;   // wave-wide: no candidate can improve
            int l = j - dl;  l = l < 0 ? 0 : l;          // clamped candidates are
            int rr = j + dl; rr = rr > 255 ? 255 : rr;   // valid upper bounds
            unsigned wl1 = gq[r1][l], wr1 = gq[r1][rr];
            unsigned wl2 = gq[r2][l], wr2 = gq[r2][rr];
            int gl = wl1 & 0x3FF;  float gl2 = (float)(gl*gl);  bool bl = (wl1 >> 15) != 0;
            int gr = wr1 & 0x3FF;  float gr2 = (float)(gr*gr);  bool br = (wr1 >> 15) != 0;
            a0 = fminf(a0, d2 + fminf(bl ? gl2 : 0.0f, br ? gr2 : 0.0f));
            a1 = fminf(a1, d2 + fminf(bl ? 0.0f : gl2, br ? 0.0f : gr2));
            gl = wl2 & 0x3FF;  gl2 = (float)(gl*gl);  bl = (wl2 >> 15) != 0;
            gr = wr2 & 0x3FF;  gr2 = (float)(gr*gr);  br = (wr2 >> 15) != 0;
            c0 = fminf(c0, d2 + fminf(bl ? gl2 : 0.0f, br ? gr2 : 0.0f));
            c1 = fminf(c1, d2 + fminf(bl ? 0.0f : gl2, br ? 0.0f : gr2));
        }
        float dt1 = hf ? (sqrtf(a0) + sqrtf(a1)) : 0.0f;
        float dt2 = hf ? (sqrtf(c0) + sqrtf(c1)) : 0.0f;
        float e1v = xv1 - yv1, e2v = xv2 - yv2;
        acc += e1v*e1v*dt1*dt1 + e2v*e2v*dt2*dt2;
    }

    // block reduction (deterministic)
    for (int off = 32; off; off >>= 1) acc += __shfl_down(acc, off, 64);
    int wid = t >> 6, lane = t & 63;
    if (lane == 0) wsum[wid] = acc;
    __syncthreads();
    if (t == 0) {
        float s = 0.0f;
        #pragma unroll
        for (int i = 0; i < 16; ++i) s += wsum[i];
        partials[blk] = s;                // every block writes its own slot
    }
}

__global__ __launch_bounds__(64) void final64(const float* __restrict__ partials,
                                              float* __restrict__ out) {
    int j = threadIdx.x;
    float s = partials[j];
    for (int off = 32; off; off >>= 1) s += __shfl_down(s, off, 64);
    if (j == 0) out[0] = s * (1.0f / (float)BHW);
}

extern "C" void kernel_launch(void* const* d_in, const int* in_sizes, int n_in,
                              void* d_out, int out_size, void* d_ws, size_t ws_size,
                              hipStream_t stream) {
    const float* x = (const float*)d_in[0];
    const float* y = (const float*)d_in[1];
    float* out = (float*)d_out;
    float* partials = (float*)d_ws;       // 64 floats

    hausdorff_fused<<<64, 1024, 0, stream>>>(x, y, partials);
    final64<<<1, 64, 0, stream>>>(partials, out);
}

// Round 8
// 19.830 us; speedup vs baseline: 1.2701x; 1.2701x over previous
//
#include <hip/hip_runtime.h>

#define BB 8
#define HH 256
#define WW 256
#define BHW (BB*HH*WW)
#define BIGV 512.0f

// ws layout:
//   [0, 2*BHW) u16   : g distance per pixel, [ip][b][h][w].  Exactly one of
//                      (fg-dist, bg-dist) is nonzero per pixel; the mask bit
//                      (recomputed from the input in row_pass) selects which.
//   then 256 ints    : per-edt-block any-fg flags (slot = blockIdx)
//   then BB*HH floats: per-row partial sums

// Vertical EDT via min-plus segmented scan, both channels in one pass.
// grid = 2(input)*8(batch)*16(col tile) = 256 blocks, 256 threads.
// thread: c = t&15 (column in tile), s = t>>4 (16-row segment).
__global__ __launch_bounds__(256) void edt_vert(const float* __restrict__ x,
                                                const float* __restrict__ y,
                                                unsigned short* __restrict__ gdist,
                                                int* __restrict__ blkflag) {
    __shared__ float Cf[2][16][16];   // [ch][seg][col]: dist from seg END to last zero (1e9 if none)
    __shared__ float Cb[2][16][16];   // [ch][seg][col]: dist from seg START to first zero
    __shared__ int sAny;

    int blk = blockIdx.x;
    int tileIdx = blk & 15;
    int b  = (blk >> 4) & 7;
    int ip = blk >> 7;
    int t = threadIdx.x;
    int c = t & 15, s = t >> 4;

    if (t == 0) sAny = 0;

    const float* src = (ip ? y : x) + (size_t)b*HH*WW + tileIdx*16 + c;

    // Load 16 rows once; keep mask bits.
    unsigned m = 0;
    const float* p = src + (size_t)(s*16)*WW;
    #pragma unroll
    for (int i = 0; i < 16; ++i) {
        if (p[(size_t)i*WW] > 0.5f) m |= (1u << i);
    }

    // Segment summaries. ch0 (fg EDT): zeros where bit CLEAR; ch1 (bg EDT): zeros where bit SET.
    unsigned invm = (~m) & 0xFFFFu;
    Cf[0][s][c] = invm ? (float)(15 - (31 - __clz((int)invm))) : 1e9f;
    Cb[0][s][c] = invm ? (float)(__ffs((int)invm) - 1)          : 1e9f;
    Cf[1][s][c] = m    ? (float)(15 - (31 - __clz((int)m)))     : 1e9f;
    Cb[1][s][c] = m    ? (float)(__ffs((int)m) - 1)             : 1e9f;
    __syncthreads();
    if (m) sAny = 1;   // benign LDS race, all writers store 1

    // Carries entering this segment — fully unrolled, predicated:
    // all ds_read addresses static -> issue together, single lgkmcnt wait.
    float e0 = BIGV, e1 = BIGV;
    #pragma unroll
    for (int sp = 0; sp < 15; ++sp) {
        float c0 = Cf[0][sp][c], c1 = Cf[1][sp][c];
        bool act = sp < s;
        e0 = act ? fminf(fminf(e0 + 16.0f, BIGV), c0) : e0;
        e1 = act ? fminf(fminf(e1 + 16.0f, BIGV), c1) : e1;
    }
    float f0 = BIGV, f1 = BIGV;
    #pragma unroll
    for (int sp = 15; sp >= 1; --sp) {
        float c0 = Cb[0][sp][c], c1 = Cb[1][sp][c];
        bool act = sp > s;
        f0 = act ? fminf(fminf(f0 + 16.0f, BIGV), c0) : f0;
        f1 = act ? fminf(fminf(f1 + 16.0f, BIGV), c1) : f1;
    }

    // Exact detail pass, both channels; store the single nonzero distance as u16.
    float b0v[16], b1v[16];
    float d0 = f0, d1 = f1;
    #pragma unroll
    for (int i = 15; i >= 0; --i) {
        bool bit = (m >> i) & 1u;
        d0 = !bit ? 0.0f : fminf(d0 + 1.0f, BIGV);
        d1 =  bit ? 0.0f : fminf(d1 + 1.0f, BIGV);
        b0v[i] = d0; b1v[i] = d1;
    }
    size_t base = (size_t)(ip*BB + b)*HH*WW + tileIdx*16 + c;
    d0 = e0; d1 = e1;
    #pragma unroll
    for (int i = 0; i < 16; ++i) {
        bool bit = (m >> i) & 1u;
        d0 = !bit ? 0.0f : fminf(d0 + 1.0f, BIGV);
        d1 =  bit ? 0.0f : fminf(d1 + 1.0f, BIGV);
        float g0 = fminf(d0, b0v[i]);   // fg-EDT dist (nonzero only on fg pixels)
        float g1 = fminf(d1, b1v[i]);   // bg-EDT dist (nonzero only on bg pixels)
        float gs = bit ? g0 : g1;       // exactly one is nonzero; mask bit selects
        gdist[base + (size_t)(s*16 + i)*WW] = (unsigned short)(int)gs;
    }

    __syncthreads();
    if (t == 0) blkflag[blk] = sAny;   // every block writes its own slot: no init needed
}

// Horizontal pass: packed-LDS min search with precomputed wave-uniform trip
// count (no per-iteration vote), fused loss + per-row partial.
__global__ __launch_bounds__(256) void row_pass(const float* __restrict__ x,
                                                const float* __restrict__ y,
                                                const unsigned short* __restrict__ gdist,
                                                const int* __restrict__ blkflag,
                                                float* __restrict__ partials) {
    __shared__ unsigned int spk[256];   // per-pixel: gx|mx<<15 | (gy|my<<15)<<16
    __shared__ float wsum[4];
    __shared__ float sF[2];
    int bh = blockIdx.x;          // b*HH + h
    int b  = bh >> 8;
    int j  = threadIdx.x;
    size_t rowoff = (size_t)bh * WW;

    float xv = x[rowoff + j];
    float yv = y[rowoff + j];
    int gx = gdist[rowoff + j];                       // x: single nonzero dist
    int gy = gdist[(size_t)BHW + rowoff + j];         // y: single nonzero dist
    bool mx = xv > 0.5f;                              // identical compare to edt_vert
    bool my = yv > 0.5f;
    spk[j] = (unsigned)(gx | ((int)mx << 15)) | ((unsigned)(gy | ((int)my << 15)) << 16);

    if (j < 64) {   // wave 0: gather has_fg flags (OR over 16 tile slots per input)
        int v = 0;
        if (j < 32) v = blkflag[((j < 16) ? 0 : 128) + b * 16 + (j & 15)];
        unsigned long long ball = __ballot(v != 0);
        if (j == 0) {
            sF[0] = (ball & 0xFFFFull) ? 1.0f : 0.0f;
            sF[1] = ((ball >> 16) & 0xFFFFull) ? 1.0f : 0.0f;
        }
    }
    __syncthreads();

    float gx2 = (float)(gx * gx), gy2 = (float)(gy * gy);   // <= 512^2, exact in f32
    float b0 = mx ? gx2 : 0.0f;   // x fg-EDT best (0 on bg pixels)
    float b1 = mx ? 0.0f : gx2;   // x bg-EDT best
    float b2 = my ? gy2 : 0.0f;   // y fg-EDT best
    float b3 = my ? 0.0f : gy2;   // y bg-EDT best

    // Wave-uniform trip count: candidates with dl^2 >= initial best never improve.
    float bmax = fmaxf(fmaxf(b0, b1), fmaxf(b2, b3));
    #pragma unroll
    for (int mk = 1; mk < 64; mk <<= 1) bmax = fmaxf(bmax, __shfl_xor(bmax, mk, 64));
    int N = (int)ceilf(sqrtf(bmax));
    N = N > 255 ? 255 : N;

    for (int dl = 1; dl <= N; ++dl) {
        float d2 = (float)(dl * dl);
        int l = j - dl;  l = l < 0 ? 0 : l;          // clamped candidates are
        int r = j + dl;  r = r > 255 ? 255 : r;      // valid upper bounds
        unsigned wl = spk[l], wr = spk[r];
        float glx = (float)(int)(wl & 0x3FFu);  glx *= glx;
        float grx = (float)(int)(wr & 0x3FFu);  grx *= grx;
        bool mlx = (wl & 0x8000u) != 0, mrx = (wr & 0x8000u) != 0;
        b0 = fminf(b0, fminf(d2 + (mlx ? glx : 0.0f), d2 + (mrx ? grx : 0.0f)));
        b1 = fminf(b1, fminf(d2 + (mlx ? 0.0f : glx), d2 + (mrx ? 0.0f : grx)));
        float gly = (float)(int)((wl >> 16) & 0x3FFu);  gly *= gly;
        float gry = (float)(int)((wr >> 16) & 0x3FFu);  gry *= gry;
        bool mly = (wl & 0x80000000u) != 0, mry = (wr & 0x80000000u) != 0;
        b2 = fminf(b2, fminf(d2 + (mly ? gly : 0.0f), d2 + (mry ? gry : 0.0f)));
        b3 = fminf(b3, fminf(d2 + (mly ? 0.0f : gly), d2 + (mry ? 0.0f : gry)));
    }

    float dtx = sF[0] != 0.0f ? (sqrtf(b0) + sqrtf(b1)) : 0.0f;
    float dty = sF[1] != 0.0f ? (sqrtf(b2) + sqrtf(b3)) : 0.0f;
    float e = xv - yv;
    float val = e * e * (dtx * dtx + dty * dty);

    for (int off = 32; off; off >>= 1) val += __shfl_down(val, off, 64);
    if ((j & 63) == 0) wsum[j >> 6] = val;
    __syncthreads();
    if (j == 0) partials[bh] = wsum[0] + wsum[1] + wsum[2] + wsum[3];
}

__global__ __launch_bounds__(256) void final_reduce(const float* __restrict__ partials,
                                                    float* __restrict__ out) {
    __shared__ float wsum[4];
    int j = threadIdx.x;
    float s = 0.0f;
    #pragma unroll
    for (int i = 0; i < 8; ++i) s += partials[i * 256 + j];
    for (int off = 32; off; off >>= 1) s += __shfl_down(s, off, 64);
    if ((j & 63) == 0) wsum[j >> 6] = s;
    __syncthreads();
    if (j == 0) out[0] = (wsum[0] + wsum[1] + wsum[2] + wsum[3]) * (1.0f / (float)BHW);
}

extern "C" void kernel_launch(void* const* d_in, const int* in_sizes, int n_in,
                              void* d_out, int out_size, void* d_ws, size_t ws_size,
                              hipStream_t stream) {
    const float* x = (const float*)d_in[0];
    const float* y = (const float*)d_in[1];
    float* out = (float*)d_out;

    char* ws = (char*)d_ws;
    unsigned short* gdist = (unsigned short*)ws;                          // 2*BHW u16
    int* blkflag = (int*)(ws + (size_t)2 * BHW * sizeof(unsigned short)); // 256 ints
    float* partials = (float*)(ws + (size_t)2 * BHW * sizeof(unsigned short) + 256 * sizeof(int));

    edt_vert<<<256, 256, 0, stream>>>(x, y, gdist, blkflag);
    row_pass<<<BB * HH, 256, 0, stream>>>(x, y, gdist, blkflag, partials);
    final_reduce<<<1, 256, 0, stream>>>(partials, out);
}

// Round 9
// 17.648 us; speedup vs baseline: 1.4271x; 1.1236x over previous
//
#include <hip/hip_runtime.h>

#define BB 8
#define HH 256
#define WW 256
#define BHW (BB*HH*WW)
#define BIGV 512.0f

// ws layout:
//   [0, 2*BHW) u16 : g distance per pixel, [ip][b][h][w] (one nonzero channel,
//                    mask recomputed in row_band selects fg/bg)
//   then 256 ints  : per-edt-block any-fg flags (slot = blockIdx)

// Vertical EDT via min-plus segmented scan (identical to the 15.3us R6 kernel,
// plus out[0] zeroing for the atomic accumulation in row_band).
__global__ __launch_bounds__(256) void edt_vert(const float* __restrict__ x,
                                                const float* __restrict__ y,
                                                unsigned short* __restrict__ gdist,
                                                int* __restrict__ blkflag,
                                                float* __restrict__ out) {
    __shared__ float Cf[2][16][16];
    __shared__ float Cb[2][16][16];
    __shared__ int sAny;

    int blk = blockIdx.x;
    int tileIdx = blk & 15;
    int b  = (blk >> 4) & 7;
    int ip = blk >> 7;
    int t = threadIdx.x;
    int c = t & 15, s = t >> 4;

    if (t == 0) sAny = 0;
    if (blk == 0 && t == 0) out[0] = 0.0f;   // stream-ordered before row_band

    const float* src = (ip ? y : x) + (size_t)b*HH*WW + tileIdx*16 + c;

    unsigned m = 0;
    const float* p = src + (size_t)(s*16)*WW;
    #pragma unroll
    for (int i = 0; i < 16; ++i) {
        if (p[(size_t)i*WW] > 0.5f) m |= (1u << i);
    }

    unsigned invm = (~m) & 0xFFFFu;
    Cf[0][s][c] = invm ? (float)(15 - (31 - __clz((int)invm))) : 1e9f;
    Cb[0][s][c] = invm ? (float)(__ffs((int)invm) - 1)          : 1e9f;
    Cf[1][s][c] = m    ? (float)(15 - (31 - __clz((int)m)))     : 1e9f;
    Cb[1][s][c] = m    ? (float)(__ffs((int)m) - 1)             : 1e9f;
    __syncthreads();
    if (m) sAny = 1;

    float e0 = BIGV, e1 = BIGV;
    #pragma unroll
    for (int sp = 0; sp < 15; ++sp) {
        float c0 = Cf[0][sp][c], c1 = Cf[1][sp][c];
        bool act = sp < s;
        e0 = act ? fminf(fminf(e0 + 16.0f, BIGV), c0) : e0;
        e1 = act ? fminf(fminf(e1 + 16.0f, BIGV), c1) : e1;
    }
    float f0 = BIGV, f1 = BIGV;
    #pragma unroll
    for (int sp = 15; sp >= 1; --sp) {
        float c0 = Cb[0][sp][c], c1 = Cb[1][sp][c];
        bool act = sp > s;
        f0 = act ? fminf(fminf(f0 + 16.0f, BIGV), c0) : f0;
        f1 = act ? fminf(fminf(f1 + 16.0f, BIGV), c1) : f1;
    }

    float b0v[16], b1v[16];
    float d0 = f0, d1 = f1;
    #pragma unroll
    for (int i = 15; i >= 0; --i) {
        bool bit = (m >> i) & 1u;
        d0 = !bit ? 0.0f : fminf(d0 + 1.0f, BIGV);
        d1 =  bit ? 0.0f : fminf(d1 + 1.0f, BIGV);
        b0v[i] = d0; b1v[i] = d1;
    }
    size_t base = (size_t)(ip*BB + b)*HH*WW + tileIdx*16 + c;
    d0 = e0; d1 = e1;
    #pragma unroll
    for (int i = 0; i < 16; ++i) {
        bool bit = (m >> i) & 1u;
        d0 = !bit ? 0.0f : fminf(d0 + 1.0f, BIGV);
        d1 =  bit ? 0.0f : fminf(d1 + 1.0f, BIGV);
        float g0 = fminf(d0, b0v[i]);
        float g1 = fminf(d1, b1v[i]);
        float gs = bit ? g0 : g1;
        gdist[base + (size_t)(s*16 + i)*WW] = (unsigned short)(int)gs;
    }

    __syncthreads();
    if (t == 0) blkflag[blk] = sAny;
}

// Banded horizontal pass: 128 blocks = b(8) x band(16), 1024 threads.
// Each block: 16 rows, processed 4-at-a-time (row slot = t>>8), R6 body per row.
// One atomicAdd per block (128 total ~ 1us; the R3/R5 failures were 2048).
__global__ __launch_bounds__(1024) void row_band(const float* __restrict__ x,
                                                 const float* __restrict__ y,
                                                 const unsigned short* __restrict__ gdist,
                                                 const int* __restrict__ blkflag,
                                                 float* __restrict__ out) {
    __shared__ float sp[4][4][768];   // [rowslot][ch][col padded]
    __shared__ float wsum[16];
    __shared__ float sF[2];
    int blk = blockIdx.x;
    int b    = blk >> 4;              // batch
    int band = blk & 15;              // 16-row band
    int t = threadIdx.x;
    int j  = t & 255;                 // column
    int rs = t >> 8;                  // row slot 0..3 (wave-uniform)

    if (t < 64) {   // first wave: gather has_fg flags (OR over 16 tile slots per input)
        int v = 0;
        if (t < 32) v = blkflag[((t < 16) ? 0 : 128) + b * 16 + (t & 15)];
        unsigned long long ball = __ballot(v != 0);
        if (t == 0) {
            sF[0] = (ball & 0xFFFFull) ? 1.0f : 0.0f;
            sF[1] = ((ball >> 16) & 0xFFFFull) ? 1.0f : 0.0f;
        }
    }

    float acc = 0.0f;
    #pragma unroll
    for (int iter = 0; iter < 4; ++iter) {
        int row = band * 16 + rs + iter * 4;          // row in image
        size_t rowoff = ((size_t)b * HH + row) * WW;

        float xv = x[rowoff + j];
        float yv = y[rowoff + j];
        int gx = gdist[rowoff + j];
        int gy = gdist[(size_t)BHW + rowoff + j];
        bool mx = xv > 0.5f;
        bool my = yv > 0.5f;
        int gx2 = gx * gx, gy2 = gy * gy;             // <= 512^2, exact in f32
        float v0 = (float)(mx ? gx2 : 0);
        float v1 = (float)(mx ? 0 : gx2);
        float v2 = (float)(my ? gy2 : 0);
        float v3 = (float)(my ? 0 : gy2);

        sp[rs][0][j] = 1e9f; sp[rs][1][j] = 1e9f; sp[rs][2][j] = 1e9f; sp[rs][3][j] = 1e9f;
        sp[rs][0][j+512] = 1e9f; sp[rs][1][j+512] = 1e9f; sp[rs][2][j+512] = 1e9f; sp[rs][3][j+512] = 1e9f;
        sp[rs][0][j+256] = v0; sp[rs][1][j+256] = v1; sp[rs][2][j+256] = v2; sp[rs][3][j+256] = v3;
        __syncthreads();

        float b0 = v0, b1 = v1, b2 = v2, b3 = v3;
        for (int dl = 1; dl < 256; ++dl) {
            float d2 = (float)(dl * dl);
            float bmax = fmaxf(fmaxf(b0, b1), fmaxf(b2, b3));
            if (!__any(d2 < bmax)) break;             // wave = one row: early exit
            int l = j + 256 - dl, r = j + 256 + dl;
            b0 = fminf(b0, fminf(d2 + sp[rs][0][l], d2 + sp[rs][0][r]));
            b1 = fminf(b1, fminf(d2 + sp[rs][1][l], d2 + sp[rs][1][r]));
            b2 = fminf(b2, fminf(d2 + sp[rs][2][l], d2 + sp[rs][2][r]));
            b3 = fminf(b3, fminf(d2 + sp[rs][3][l], d2 + sp[rs][3][r]));
        }

        float dtx = sF[0] != 0.0f ? (sqrtf(b0) + sqrtf(b1)) : 0.0f;
        float dty = sF[1] != 0.0f ? (sqrtf(b2) + sqrtf(b3)) : 0.0f;
        float e = xv - yv;
        acc += e * e * (dtx * dtx + dty * dty);
        __syncthreads();                               // protect sp before next overwrite
    }

    for (int off = 32; off; off >>= 1) acc += __shfl_down(acc, off, 64);
    int wid = t >> 6, lane = t & 63;
    if (lane == 0) wsum[wid] = acc;
    __syncthreads();
    if (t == 0) {
        float s = 0.0f;
        #pragma unroll
        for (int i = 0; i < 16; ++i) s += wsum[i];
        atomicAdd(out, s * (1.0f / (float)BHW));       // 128 atomics total
    }
}

extern "C" void kernel_launch(void* const* d_in, const int* in_sizes, int n_in,
                              void* d_out, int out_size, void* d_ws, size_t ws_size,
                              hipStream_t stream) {
    const float* x = (const float*)d_in[0];
    const float* y = (const float*)d_in[1];
    float* out = (float*)d_out;

    char* ws = (char*)d_ws;
    unsigned short* gdist = (unsigned short*)ws;                          // 2*BHW u16
    int* blkflag = (int*)(ws + (size_t)2 * BHW * sizeof(unsigned short)); // 256 ints

    edt_vert<<<256, 256, 0, stream>>>(x, y, gdist, blkflag, out);
    row_band<<<128, 1024, 0, stream>>>(x, y, gdist, blkflag, out);
}

// Round 10
// 15.966 us; speedup vs baseline: 1.5775x; 1.1054x over previous
//
#include <hip/hip_runtime.h>

#define BB 8
#define HH 256
#define WW 256
#define BHW (BB*HH*WW)
#define BIGV 512.0f

// ws layout:
//   [0, 2*BHW) u16   : g distance per pixel, [ip][b][h][w] (one nonzero channel;
//                      mask recomputed from input in row_pass selects fg/bg)
//   then 256 ints    : per-edt-block any-fg flags (slot = blockIdx)
//   then BB*HH floats: per-row partial sums

// Vertical EDT via min-plus segmented scan (identical to the 15.3us R6 kernel).
__global__ __launch_bounds__(256) void edt_vert(const float* __restrict__ x,
                                                const float* __restrict__ y,
                                                unsigned short* __restrict__ gdist,
                                                int* __restrict__ blkflag) {
    __shared__ float Cf[2][16][16];
    __shared__ float Cb[2][16][16];
    __shared__ int sAny;

    int blk = blockIdx.x;
    int tileIdx = blk & 15;
    int b  = (blk >> 4) & 7;
    int ip = blk >> 7;
    int t = threadIdx.x;
    int c = t & 15, s = t >> 4;

    if (t == 0) sAny = 0;

    const float* src = (ip ? y : x) + (size_t)b*HH*WW + tileIdx*16 + c;

    unsigned m = 0;
    const float* p = src + (size_t)(s*16)*WW;
    #pragma unroll
    for (int i = 0; i < 16; ++i) {
        if (p[(size_t)i*WW] > 0.5f) m |= (1u << i);
    }

    unsigned invm = (~m) & 0xFFFFu;
    Cf[0][s][c] = invm ? (float)(15 - (31 - __clz((int)invm))) : 1e9f;
    Cb[0][s][c] = invm ? (float)(__ffs((int)invm) - 1)          : 1e9f;
    Cf[1][s][c] = m    ? (float)(15 - (31 - __clz((int)m)))     : 1e9f;
    Cb[1][s][c] = m    ? (float)(__ffs((int)m) - 1)             : 1e9f;
    __syncthreads();
    if (m) sAny = 1;   // benign LDS race, all writers store 1

    float e0 = BIGV, e1 = BIGV;
    #pragma unroll
    for (int sp = 0; sp < 15; ++sp) {
        float c0 = Cf[0][sp][c], c1 = Cf[1][sp][c];
        bool act = sp < s;
        e0 = act ? fminf(fminf(e0 + 16.0f, BIGV), c0) : e0;
        e1 = act ? fminf(fminf(e1 + 16.0f, BIGV), c1) : e1;
    }
    float f0 = BIGV, f1 = BIGV;
    #pragma unroll
    for (int sp = 15; sp >= 1; --sp) {
        float c0 = Cb[0][sp][c], c1 = Cb[1][sp][c];
        bool act = sp > s;
        f0 = act ? fminf(fminf(f0 + 16.0f, BIGV), c0) : f0;
        f1 = act ? fminf(fminf(f1 + 16.0f, BIGV), c1) : f1;
    }

    float b0v[16], b1v[16];
    float d0 = f0, d1 = f1;
    #pragma unroll
    for (int i = 15; i >= 0; --i) {
        bool bit = (m >> i) & 1u;
        d0 = !bit ? 0.0f : fminf(d0 + 1.0f, BIGV);
        d1 =  bit ? 0.0f : fminf(d1 + 1.0f, BIGV);
        b0v[i] = d0; b1v[i] = d1;
    }
    size_t base = (size_t)(ip*BB + b)*HH*WW + tileIdx*16 + c;
    d0 = e0; d1 = e1;
    #pragma unroll
    for (int i = 0; i < 16; ++i) {
        bool bit = (m >> i) & 1u;
        d0 = !bit ? 0.0f : fminf(d0 + 1.0f, BIGV);
        d1 =  bit ? 0.0f : fminf(d1 + 1.0f, BIGV);
        float g0 = fminf(d0, b0v[i]);
        float g1 = fminf(d1, b1v[i]);
        float gs = bit ? g0 : g1;
        gdist[base + (size_t)(s*16 + i)*WW] = (unsigned short)(int)gs;
    }

    __syncthreads();
    if (t == 0) blkflag[blk] = sAny;
}

// Horizontal pass: R6 body, but LDS channels interleaved as float2 pairs so the
// dl-loop issues 4x ds_read_b64 instead of 8x ds_read_b32 (same arithmetic,
// same padding, same per-iteration vote exit).
__global__ __launch_bounds__(256) void row_pass(const float* __restrict__ x,
                                                const float* __restrict__ y,
                                                const unsigned short* __restrict__ gdist,
                                                const int* __restrict__ blkflag,
                                                float* __restrict__ partials) {
    __shared__ float2 spA[768];   // x: (fg^2, bg^2) per pixel, padded +-256
    __shared__ float2 spB[768];   // y: (fg^2, bg^2)
    __shared__ float wsum[4];
    __shared__ float sF[2];
    int bh = blockIdx.x;          // b*HH + h
    int b  = bh >> 8;
    int j  = threadIdx.x;
    size_t rowoff = (size_t)bh * WW;

    float xv = x[rowoff + j];
    float yv = y[rowoff + j];
    int gx = gdist[rowoff + j];
    int gy = gdist[(size_t)BHW + rowoff + j];
    bool mx = xv > 0.5f;                              // identical compare to edt_vert
    bool my = yv > 0.5f;
    int gx2 = gx * gx, gy2 = gy * gy;                 // <= 512^2, exact in f32
    float v0 = (float)(mx ? gx2 : 0);                 // x fg-EDT g^2
    float v1 = (float)(mx ? 0 : gx2);                 // x bg-EDT g^2
    float v2 = (float)(my ? gy2 : 0);                 // y fg-EDT g^2
    float v3 = (float)(my ? 0 : gy2);                 // y bg-EDT g^2

    float2 big2 = make_float2(1e9f, 1e9f);
    spA[j] = big2;      spB[j] = big2;
    spA[j+512] = big2;  spB[j+512] = big2;
    spA[j+256] = make_float2(v0, v1);
    spB[j+256] = make_float2(v2, v3);

    if (j < 64) {   // wave 0: gather has_fg flags (OR over 16 tile slots per input)
        int v = 0;
        if (j < 32) v = blkflag[((j < 16) ? 0 : 128) + b * 16 + (j & 15)];
        unsigned long long ball = __ballot(v != 0);
        if (j == 0) {
            sF[0] = (ball & 0xFFFFull) ? 1.0f : 0.0f;
            sF[1] = ((ball >> 16) & 0xFFFFull) ? 1.0f : 0.0f;
        }
    }
    __syncthreads();

    float b0 = v0, b1 = v1, b2 = v2, b3 = v3;
    for (int dl = 1; dl < 256; ++dl) {
        float d2 = (float)(dl * dl);
        float bmax = fmaxf(fmaxf(b0, b1), fmaxf(b2, b3));
        if (!__any(d2 < bmax)) break;     // no candidate can improve any lane in wave
        int l = j + 256 - dl, r = j + 256 + dl;
        float2 LA = spA[l], RA = spA[r];
        float2 LB = spB[l], RB = spB[r];
        b0 = fminf(b0, d2 + fminf(LA.x, RA.x));
        b1 = fminf(b1, d2 + fminf(LA.y, RA.y));
        b2 = fminf(b2, d2 + fminf(LB.x, RB.x));
        b3 = fminf(b3, d2 + fminf(LB.y, RB.y));
    }

    float dtx = sF[0] != 0.0f ? (sqrtf(b0) + sqrtf(b1)) : 0.0f;
    float dty = sF[1] != 0.0f ? (sqrtf(b2) + sqrtf(b3)) : 0.0f;
    float e = xv - yv;
    float val = e * e * (dtx * dtx + dty * dty);

    for (int off = 32; off; off >>= 1) val += __shfl_down(val, off, 64);
    if ((j & 63) == 0) wsum[j >> 6] = val;
    __syncthreads();
    if (j == 0) partials[bh] = wsum[0] + wsum[1] + wsum[2] + wsum[3];
}

__global__ __launch_bounds__(256) void final_reduce(const float* __restrict__ partials,
                                                    float* __restrict__ out) {
    __shared__ float wsum[4];
    int j = threadIdx.x;
    float s = 0.0f;
    #pragma unroll
    for (int i = 0; i < 8; ++i) s += partials[i * 256 + j];
    for (int off = 32; off; off >>= 1) s += __shfl_down(s, off, 64);
    if ((j & 63) == 0) wsum[j >> 6] = s;
    __syncthreads();
    if (j == 0) out[0] = (wsum[0] + wsum[1] + wsum[2] + wsum[3]) * (1.0f / (float)BHW);
}

extern "C" void kernel_launch(void* const* d_in, const int* in_sizes, int n_in,
                              void* d_out, int out_size, void* d_ws, size_t ws_size,
                              hipStream_t stream) {
    const float* x = (const float*)d_in[0];
    const float* y = (const float*)d_in[1];
    float* out = (float*)d_out;

    char* ws = (char*)d_ws;
    unsigned short* gdist = (unsigned short*)ws;                          // 2*BHW u16
    int* blkflag = (int*)(ws + (size_t)2 * BHW * sizeof(unsigned short)); // 256 ints
    float* partials = (float*)(ws + (size_t)2 * BHW * sizeof(unsigned short) + 256 * sizeof(int));

    edt_vert<<<256, 256, 0, stream>>>(x, y, gdist, blkflag);
    row_pass<<<BB * HH, 256, 0, stream>>>(x, y, gdist, blkflag, partials);
    final_reduce<<<1, 256, 0, stream>>>(partials, out);
}